// Round 4
// baseline (276.323 us; speedup 1.0000x reference)
//
#include <hip/hip_runtime.h>
#include <hip/hip_bf16.h>

// mp: [1, 21, 16, 256, 256] fp32
#define CC   21
#define DD   16
#define HH   256
#define WW   256
#define HWP  (HH * WW)      // 65536
#define DHW  (DD * HWP)     // 1048576

// Tile: D-half 8 (+4 halo = 12), H 4 (+4 = 8), W 32 (+4, padded to 36)
#define TW 32
#define TH 4
#define DT 8
#define DP2 12
#define HP 8
#define WP 36
#define A_SZ (DP2 * HP * WP)   // 3456 raw padded floats
#define C_SZ (DP2 * TH * WP)   // 1728 WH-blurred floats (rows padded to 36)
#define NTHR 512
#define K_IT 7                 // ceil(A_SZ / 512); tail = 384 = 6 full waves

typedef const __attribute__((address_space(1))) void* gp_t;
typedef __attribute__((address_space(3))) void* lp_t;

__device__ __forceinline__ void async_copy(const float* g, float* l) {
    // async global->LDS, 4B/lane; LDS dest is wave-uniform base + lane*4,
    // which our (tid + k*512) contiguous mapping satisfies exactly.
    __builtin_amdgcn_global_load_lds((gp_t)g, (lp_t)l, 4, 0, 0);
}

// Fused separable 5^3 box blur (replicate pad) + streaming weighted median.
// 1/125 cancels under normalization; normalizer = blur(sum_c mp) by linearity.
// 3-stage software pipeline, ONE barrier per phase:
//   phase p:  S: stage image p   (async global->LDS into A[p&1])
//             W: W+H blur img p-1 (A[(p-1)&1] -> C[(p-1)&1])
//             D: D blur + median img p-2 (C[p&1] -> registers)
__global__ __launch_bounds__(512, 6) void fused_kernel(const float* __restrict__ mp,
                                                       float* __restrict__ out) {
    __shared__ float Ab[2][A_SZ];
    __shared__ float Cb[2][C_SZ];

    const int w0 = blockIdx.x * TW;
    const int h0 = blockIdx.y * TH;
    const int dbase = blockIdx.z * DT;    // 0 or 8
    const int tid = threadIdx.x;
    const int x  = tid & 31;
    const int yy = (tid >> 5) & 3;
    const int dg = tid >> 7;              // 0..3
    const int d0 = dg * 2;                // 2 output planes per thread

    // ---- precompute clamped staging element-offsets (replicate padding) ----
    int off[K_IT];
#pragma unroll
    for (int k = 0; k < K_IT; ++k) {
        int i = tid + k * NTHR;
        if (i < A_SZ) {
            int dz  = i / (HP * WP);
            int rem = i - dz * (HP * WP);
            int py  = rem / WP;
            int px  = rem - py * WP;
            int d = min(DD - 1, max(0, dbase + dz - 2));
            int h = min(HH - 1, max(0, h0 + py - 2));
            int w = min(WW - 1, max(0, w0 + px - 2));
            off[k] = d * HWP + h * WW + w;
        } else {
            off[k] = 0;
        }
    }

    float inv[2], s[2], v0[2], v1[2];
    int m0[2], m1[2];

    for (int ph = 0; ph < CC + 3; ++ph) {   // 24 phases, 1 barrier each
        // ======== S(ph): stage image ph into A[ph&1] ========
        if (ph == 0) {
            // channel-sum image (normalizer) — via VGPR accumulate
            float* Adst = Ab[0];
#pragma unroll
            for (int k = 0; k < K_IT; ++k) {
                int i = tid + k * NTHR;
                if (i < A_SZ) {
                    const float* p = mp + off[k];
                    float t0 = 0.f, t1 = 0.f, t2 = 0.f;
                    t0 = p[0];
#pragma unroll
                    for (int c = 1; c < CC; c += 2) {
                        t1 += p[(size_t)c * DHW];
                        t2 += p[(size_t)(c + 1) * DHW];
                    }
                    Adst[i] = t0 + t1 + t2;
                }
            }
        } else if (ph <= CC) {
            const float* src = mp + (size_t)(ph - 1) * DHW;
            float* Adst = Ab[ph & 1];
#pragma unroll
            for (int k = 0; k < 6; ++k)
                async_copy(src + off[k], &Adst[tid + k * NTHR]);
            if (tid < A_SZ - 6 * NTHR)   // 384 = waves 0..5, whole waves
                async_copy(src + off[6], &Adst[tid + 6 * NTHR]);
        }

        // ======== W(ph-1): W+H blur, A -> C (192 threads, 8 outputs each) ====
        if (ph >= 1 && ph <= CC + 1 && tid < 192) {
            const float* Ac = Ab[(ph - 1) & 1];
            float* Cc = Cb[(ph - 1) & 1];
            const int row = tid >> 2;          // 0..47 = plane*4 + y
            const int x0  = (tid & 3) * 8;
            const int pl  = row >> 2;
            const int y_  = row & 3;
            const float* ab = Ac + (pl * HP + y_) * WP + x0;
            float4 a0 = *(const float4*)(ab);
            float4 a1 = *(const float4*)(ab + 4);
            float4 a2 = *(const float4*)(ab + 8);
#pragma unroll
            for (int j = 1; j < 5; ++j) {
                ab += WP;
                float4 b0 = *(const float4*)(ab);
                float4 b1 = *(const float4*)(ab + 4);
                float4 b2 = *(const float4*)(ab + 8);
                a0.x += b0.x; a0.y += b0.y; a0.z += b0.z; a0.w += b0.w;
                a1.x += b1.x; a1.y += b1.y; a1.z += b1.z; a1.w += b1.w;
                a2.x += b2.x; a2.y += b2.y; a2.z += b2.z; a2.w += b2.w;
            }
            const float t0 = a0.x, t1 = a0.y, t2 = a0.z, t3 = a0.w;
            const float t4 = a1.x, t5 = a1.y, t6 = a1.z, t7 = a1.w;
            const float t8 = a2.x, t9 = a2.y, t10 = a2.z, t11 = a2.w;
            float4 o0, o1;
            o0.x = t0 + t1 + t2 + t3 + t4;
            o0.y = t1 + t2 + t3 + t4 + t5;
            o0.z = t2 + t3 + t4 + t5 + t6;
            o0.w = t3 + t4 + t5 + t6 + t7;
            o1.x = t4 + t5 + t6 + t7 + t8;
            o1.y = t5 + t6 + t7 + t8 + t9;
            o1.z = t6 + t7 + t8 + t9 + t10;
            o1.w = t7 + t8 + t9 + t10 + t11;
            *(float4*)(Cc + row * WP + x0)     = o0;
            *(float4*)(Cc + row * WP + x0 + 4) = o1;
        }

        // ======== D(ph-2): D blur + streaming median (all 512 threads) ======
        if (ph >= 2) {
            const int img = ph - 2;
            const float* Cc = Cb[img & 1];
            float c0 = Cc[((d0 + 0) * TH + yy) * WP + x];
            float c1 = Cc[((d0 + 1) * TH + yy) * WP + x];
            float c2 = Cc[((d0 + 2) * TH + yy) * WP + x];
            float c3 = Cc[((d0 + 3) * TH + yy) * WP + x];
            float c4 = Cc[((d0 + 4) * TH + yy) * WP + x];
            float c5 = Cc[((d0 + 5) * TH + yy) * WP + x];
            float rr[2];
            rr[0] = c0 + c1 + c2 + c3 + c4;
            rr[1] = c1 + c2 + c3 + c4 + c5;
            if (img == 0) {
                inv[0] = 1.0f / rr[0]; inv[1] = 1.0f / rr[1];
                s[0] = s[1] = 0.f;
                m0[0] = m0[1] = 0; m1[0] = m1[1] = 0;
                v0[0] = v0[1] = 0.f; v1[0] = v1[1] = 0.f;
            } else {
                const int cch = img - 1;
#pragma unroll
                for (int p = 0; p < 2; ++p) {
                    float yn = rr[p] * inv[p];
                    float sn = s[p] + yn;
                    if (cch == 0) { v0[p] = yn; v1[p] = yn; }                       // defaults
                    if (yn > 0.f && sn < 0.5f) { m0[p] = cch; v0[p] = yn; }         // last qualifying
                    if (m1[p] == 0 && cch > 0 && sn > 0.5f) { m1[p] = cch; v1[p] = yn; } // first qualifying
                    s[p] = sn;
                }
            }
        }

        __syncthreads();
    }

    // ======== write out: keep med0/med1 channels, zero elsewhere ========
    const int rowbase = (h0 + yy) * WW + w0 + x;
    const int dout0 = dbase + d0;
#pragma unroll
    for (int cch = 0; cch < CC; ++cch) {
#pragma unroll
        for (int p = 0; p < 2; ++p) {
            float v = (cch == m0[p]) ? v0[p]
                    : ((cch == m1[p]) ? v1[p] : 0.f);
            out[(size_t)cch * DHW + (dout0 + p) * HWP + rowbase] = v;
        }
    }
}

extern "C" void kernel_launch(void* const* d_in, const int* in_sizes, int n_in,
                              void* d_out, int out_size, void* d_ws, size_t ws_size,
                              hipStream_t stream) {
    const float* mp = (const float*)d_in[0];
    float* out = (float*)d_out;

    dim3 grid(WW / TW, HH / TH, DD / DT);   // 8 x 64 x 2 = 1024 blocks
    fused_kernel<<<grid, NTHR, 0, stream>>>(mp, out);
}

// Round 5
// 215.813 us; speedup vs baseline: 1.2804x; 1.2804x over previous
//
#include <hip/hip_runtime.h>
#include <hip/hip_bf16.h>

// mp: [1, 21, 16, 256, 256] fp32
#define CC   21
#define DD   16
#define HH   256
#define WW   256
#define HWP  (HH * WW)      // 65536
#define DHW  (DD * HWP)     // 1048576

// K_blur tile: one channel, full D (16), H 4, W 32. Single-shot block, 2 barriers.
#define TW 32
#define TH 4
#define AROW 40              // LDS row [w0-4 .. w0+35]; data at j=2..37; 16B-aligned f4 slots
#define NROW 160             // 20 d-planes x 8 h-rows
#define A_SZ (NROW * AROW)   // 6400 floats = 25.6 KB
#define C_SZ (20 * TH * TW)  // 2560 floats = 10.2 KB

// Separable 5^3 box blur, replicate padding, one channel-tile per block.
// Writes RAW blurred sums (1/125 dropped — cancels under normalization) to out.
__global__ __launch_bounds__(256) void blur_kernel(const float* __restrict__ mp,
                                                   float* __restrict__ out) {
    __shared__ float A[A_SZ];
    __shared__ float C[C_SZ];

    const int w0 = blockIdx.x * TW;
    const int h0 = blockIdx.y * TH;
    const int ch = blockIdx.z;
    const int tid = threadIdx.x;
    const float* __restrict__ src = mp + (size_t)ch * DHW;

    // ---- stage: interior as float4 (1280 tasks), edges scalar (640 tasks) ----
#pragma unroll
    for (int k = 0; k < 5; ++k) {
        int i = tid + k * 256;
        int r = i >> 3, sg = i & 7;          // r: 0..159 = dz*8+py ; sg: x-quad
        int dz = r >> 3, py = r & 7;
        int d = min(DD - 1, max(0, dz - 2));
        int h = min(HH - 1, max(0, h0 + py - 2));
        float4 v = *(const float4*)(src + d * HWP + h * WW + w0 + sg * 4);
        *(float4*)(&A[r * AROW + 4 + sg * 4]) = v;   // j = 4+sg*4 <-> w = w0+sg*4
    }
    for (int i = tid; i < 640; i += 256) {
        int r = i >> 2, e = i & 3;
        int dz = r >> 3, py = r & 7;
        int d = min(DD - 1, max(0, dz - 2));
        int h = min(HH - 1, max(0, h0 + py - 2));
        int we = (e < 2) ? (w0 + e - 2) : (w0 + 30 + e);   // w0-2,w0-1,w0+32,w0+33
        int w = min(WW - 1, max(0, we));
        int j = (e < 2) ? (2 + e) : (34 + e);              // 2,3,36,37
        A[r * AROW + j] = src[d * HWP + h * WW + w];
    }
    __syncthreads();

    // ---- WH pass: 320 octet tasks -> C[cz 0..19][y 0..3][x 0..31] ----
    for (int i = tid; i < 320; i += 256) {
        int row = i >> 2;                    // cz*4 + y
        int x0  = (i & 3) * 8;
        int cz = row >> 2, y = row & 3;
        float hs[16];
#pragma unroll
        for (int q = 0; q < 16; ++q) hs[q] = 0.f;
#pragma unroll
        for (int k = 0; k < 5; ++k) {        // H blur: A h-rows y..y+4
            const float* a = &A[(cz * 8 + y + k) * AROW + x0];
#pragma unroll
            for (int q = 0; q < 16; q += 4) {
                float4 v = *(const float4*)(a + q);
                hs[q] += v.x; hs[q + 1] += v.y; hs[q + 2] += v.z; hs[q + 3] += v.w;
            }
        }
        // W blur: out x = x0+kk uses hs[kk+2..kk+6]  (j = x0+q <-> w = w0+x0+q-4)
#pragma unroll
        for (int kk = 0; kk < 8; ++kk)
            C[(cz * TH + y) * TW + x0 + kk] =
                hs[kk + 2] + hs[kk + 3] + hs[kk + 4] + hs[kk + 5] + hs[kk + 6];
    }
    __syncthreads();

    // ---- D pass: sliding window over C, store raw blurred to global ----
    const int x = tid & 31, yy = (tid >> 5) & 3, dg = tid >> 7;
    const int d0 = dg * 8;
    float val[12];
#pragma unroll
    for (int m = 0; m < 12; ++m)
        val[m] = C[((d0 + m) * TH + yy) * TW + x];
    float* __restrict__ dst = out + (size_t)ch * DHW + (h0 + yy) * WW + w0 + x;
#pragma unroll
    for (int p = 0; p < 8; ++p)
        dst[(size_t)(d0 + p) * HWP] = val[p] + val[p + 1] + val[p + 2] + val[p + 3] + val[p + 4];
}

// K_med: per 4-pixel group, in place on the raw blurred values in out.
// total = sum_c blur_c (no separate sum-image needed). No LDS, no barriers.
__global__ __launch_bounds__(256) void median_kernel(float* __restrict__ y4) {
    const size_t i = (size_t)blockIdx.x * 256 + threadIdx.x;   // 0..262143
    const size_t base = i * 4;

    float v[CC][4];
    float tot[4] = {0.f, 0.f, 0.f, 0.f};
#pragma unroll
    for (int c = 0; c < CC; ++c) {
        float4 t = *(const float4*)(y4 + (size_t)c * DHW + base);
        v[c][0] = t.x; v[c][1] = t.y; v[c][2] = t.z; v[c][3] = t.w;
#pragma unroll
        for (int p = 0; p < 4; ++p) tot[p] += v[c][p];
    }
    float inv[4];
#pragma unroll
    for (int p = 0; p < 4; ++p) inv[p] = 1.0f / tot[p];

    float s[4] = {0.f, 0.f, 0.f, 0.f};
    float v0[4], v1[4];
    int m0[4] = {0, 0, 0, 0}, m1[4] = {0, 0, 0, 0};
#pragma unroll
    for (int c = 0; c < CC; ++c) {
#pragma unroll
        for (int p = 0; p < 4; ++p) {
            float yn = v[c][p] * inv[p];
            float sn = s[p] + yn;
            if (c == 0) { v0[p] = yn; v1[p] = yn; }                         // defaults
            if (v[c][p] > 0.f && sn < 0.5f) { m0[p] = c; v0[p] = yn; }      // last qualifying
            if (m1[p] == 0 && c > 0 && sn > 0.5f) { m1[p] = c; v1[p] = yn; } // first qualifying
            s[p] = sn;
        }
    }

#pragma unroll
    for (int c = 0; c < CC; ++c) {
        float4 o;
        o.x = (c == m0[0]) ? v0[0] : ((c == m1[0]) ? v1[0] : 0.f);
        o.y = (c == m0[1]) ? v0[1] : ((c == m1[1]) ? v1[1] : 0.f);
        o.z = (c == m0[2]) ? v0[2] : ((c == m1[2]) ? v1[2] : 0.f);
        o.w = (c == m0[3]) ? v0[3] : ((c == m1[3]) ? v1[3] : 0.f);
        *(float4*)(y4 + (size_t)c * DHW + base) = o;
    }
}

extern "C" void kernel_launch(void* const* d_in, const int* in_sizes, int n_in,
                              void* d_out, int out_size, void* d_ws, size_t ws_size,
                              hipStream_t stream) {
    const float* mp = (const float*)d_in[0];
    float* out = (float*)d_out;

    dim3 bgrid(WW / TW, HH / TH, CC);          // 8 x 64 x 21 = 10752 blocks
    blur_kernel<<<bgrid, 256, 0, stream>>>(mp, out);

    median_kernel<<<(DHW / 4) / 256, 256, 0, stream>>>(out);   // 1024 blocks
}

// Round 6
// 210.187 us; speedup vs baseline: 1.3147x; 1.0268x over previous
//
#include <hip/hip_runtime.h>
#include <hip/hip_bf16.h>

// mp: [1, 21, 16, 256, 256] fp32
#define CC   21
#define DD   16
#define HH   256
#define WW   256
#define HWP  (HH * WW)      // 65536
#define DHW  (DD * HWP)     // 1048576

// K_blur tile: one channel, full D (16), H 4, W 32. Single-shot block, 2 barriers.
// A layout: h-major rows ar = py*20 + dz (py 0..7, dz 0..19), row stride 44 floats
//   (bank stride 12 -> 8 consecutive rows cover all 32 banks for b128 ops).
//   Within a row: j = (w - w0) + 4, valid j = 2..37 (interior j=4..35 16B-aligned).
// C layout: out-row major, row = y*20 + dz, stride 33 (scalar access, conflict-free).
#define TW 32
#define TH 4
#define AROW 44
#define NR 160               // 8 py * 20 dz
#define A_SZ (NR * AROW)     // 7040 floats = 28.2 KB
#define CROW 33
#define C_SZ (80 * CROW)     // 2640 floats = 10.6 KB   (total 38.7 KB -> 4 blocks/CU)

// Separable 5^3 box blur, replicate padding, one channel-tile per block.
// Writes RAW blurred sums (1/125 dropped — cancels under normalization) to out.
__global__ __launch_bounds__(256) void blur_kernel(const float* __restrict__ mp,
                                                   float* __restrict__ out) {
    __shared__ float A[A_SZ];
    __shared__ float C[C_SZ];

    const int w0 = blockIdx.x * TW;
    const int h0 = blockIdx.y * TH;
    const int ch = blockIdx.z;
    const int tid = threadIdx.x;
    const float* __restrict__ src = mp + (size_t)ch * DHW;

    // ---- stage interior: 160 rows x 8 float4-quads = 1280 tasks ----
#pragma unroll
    for (int k = 0; k < 5; ++k) {
        int i = tid + k * 256;
        int r = i >> 3, sg = i & 7;          // r = py*20 + dz
        int py = r / 20, dz = r - py * 20;
        int d = min(DD - 1, max(0, dz - 2));
        int h = min(HH - 1, max(0, h0 + py - 2));
        float4 v = *(const float4*)(src + d * HWP + h * WW + w0 + sg * 4);
        *(float4*)(&A[r * AROW + 4 + sg * 4]) = v;   // j = 4+sg*4 <-> w = w0+sg*4
    }
    // ---- stage edges: 160 rows x 4 edge elems (j = 2,3,36,37) ----
    for (int i = tid; i < 640; i += 256) {
        int r = i >> 2, e = i & 3;
        int py = r / 20, dz = r - py * 20;
        int d = min(DD - 1, max(0, dz - 2));
        int h = min(HH - 1, max(0, h0 + py - 2));
        int we = (e < 2) ? (w0 + e - 2) : (w0 + 30 + e);   // w0-2,w0-1,w0+32,w0+33
        int w = min(WW - 1, max(0, we));
        int j = (e < 2) ? (2 + e) : (34 + e);              // 2,3,36,37
        A[r * AROW + j] = src[d * HWP + h * WW + w];
    }
    __syncthreads();

    // ---- WH pass: 320 octet tasks; row = y*20 + dz (y 0..3, dz 0..19), quad x0 ----
    for (int t = tid; t < 320; t += 256) {
        int quad = t / 80;
        int row  = t - quad * 80;            // y*20 + dz
        int x0   = quad * 8;
        float hs[16];
#pragma unroll
        for (int q = 0; q < 16; ++q) hs[q] = 0.f;
#pragma unroll
        for (int k = 0; k < 5; ++k) {        // H blur: ar = row + 20k  (py = y+k)
            const float* a = &A[(row + 20 * k) * AROW + x0];   // j = x0 .. x0+15
#pragma unroll
            for (int q = 0; q < 16; q += 4) {
                float4 v = *(const float4*)(a + q);
                hs[q] += v.x; hs[q + 1] += v.y; hs[q + 2] += v.z; hs[q + 3] += v.w;
            }
        }
        // W blur: out x = x0+kk needs j = x0+kk+2 .. x0+kk+6 -> hs[kk+2..kk+6]
#pragma unroll
        for (int kk = 0; kk < 8; ++kk)
            C[row * CROW + x0 + kk] =
                hs[kk + 2] + hs[kk + 3] + hs[kk + 4] + hs[kk + 5] + hs[kk + 6];
    }
    __syncthreads();

    // ---- D pass: sliding window over C, store raw blurred to global ----
    const int x = tid & 31, yy = (tid >> 5) & 3, dg = tid >> 7;
    const int d0 = dg * 8;
    float val[12];
#pragma unroll
    for (int m = 0; m < 12; ++m)
        val[m] = C[(yy * 20 + d0 + m) * CROW + x];
    float* __restrict__ dst = out + (size_t)ch * DHW + (h0 + yy) * WW + w0 + x;
#pragma unroll
    for (int p = 0; p < 8; ++p)
        dst[(size_t)(d0 + p) * HWP] = val[p] + val[p + 1] + val[p + 2] + val[p + 3] + val[p + 4];
}

// K_med: per 4-pixel group, in place on the raw blurred values in out.
// total = sum_c blur_c (no separate sum-image needed). No LDS, no barriers.
__global__ __launch_bounds__(256) void median_kernel(float* __restrict__ y4) {
    const size_t i = (size_t)blockIdx.x * 256 + threadIdx.x;   // 0..262143
    const size_t base = i * 4;

    float v[CC][4];
    float tot[4] = {0.f, 0.f, 0.f, 0.f};
#pragma unroll
    for (int c = 0; c < CC; ++c) {
        float4 t = *(const float4*)(y4 + (size_t)c * DHW + base);
        v[c][0] = t.x; v[c][1] = t.y; v[c][2] = t.z; v[c][3] = t.w;
#pragma unroll
        for (int p = 0; p < 4; ++p) tot[p] += v[c][p];
    }
    float inv[4];
#pragma unroll
    for (int p = 0; p < 4; ++p) inv[p] = 1.0f / tot[p];

    float s[4] = {0.f, 0.f, 0.f, 0.f};
    float v0[4], v1[4];
    int m0[4] = {0, 0, 0, 0}, m1[4] = {0, 0, 0, 0};
#pragma unroll
    for (int c = 0; c < CC; ++c) {
#pragma unroll
        for (int p = 0; p < 4; ++p) {
            float yn = v[c][p] * inv[p];
            float sn = s[p] + yn;
            if (c == 0) { v0[p] = yn; v1[p] = yn; }                         // defaults
            if (v[c][p] > 0.f && sn < 0.5f) { m0[p] = c; v0[p] = yn; }      // last qualifying
            if (m1[p] == 0 && c > 0 && sn > 0.5f) { m1[p] = c; v1[p] = yn; } // first qualifying
            s[p] = sn;
        }
    }

#pragma unroll
    for (int c = 0; c < CC; ++c) {
        float4 o;
        o.x = (c == m0[0]) ? v0[0] : ((c == m1[0]) ? v1[0] : 0.f);
        o.y = (c == m0[1]) ? v0[1] : ((c == m1[1]) ? v1[1] : 0.f);
        o.z = (c == m0[2]) ? v0[2] : ((c == m1[2]) ? v1[2] : 0.f);
        o.w = (c == m0[3]) ? v0[3] : ((c == m1[3]) ? v1[3] : 0.f);
        *(float4*)(y4 + (size_t)c * DHW + base) = o;
    }
}

extern "C" void kernel_launch(void* const* d_in, const int* in_sizes, int n_in,
                              void* d_out, int out_size, void* d_ws, size_t ws_size,
                              hipStream_t stream) {
    const float* mp = (const float*)d_in[0];
    float* out = (float*)d_out;

    dim3 bgrid(WW / TW, HH / TH, CC);          // 8 x 64 x 21 = 10752 blocks
    blur_kernel<<<bgrid, 256, 0, stream>>>(mp, out);

    median_kernel<<<(DHW / 4) / 256, 256, 0, stream>>>(out);   // 1024 blocks
}